// Round 10
// baseline (317.445 us; speedup 1.0000x reference)
//
#include <hip/hip_runtime.h>
#include <stdint.h>

#define HW   1369      // 37*37 output pixels
#define QW   39        // padded row width
#define QP   1616      // padded plane rows per (b) in Xp
#define QT   1536      // q rows in x1 (per batch)
#define CIN  1024
#define CMID 512
#define KTOT 9216      // 9 * 1024
#define NTIL 144       // K-tiles: 16 cblocks(64) * 9 taps, cblock-major tap-inner
#define ASL  12288     // A slot stride (elements): 192 x 64 (24 KB)
#define BBASE 36864    // B region base (elements) = 3 * ASL
#define BSL  16384     // B slot stride (elements): 256 x 64 (32 KB)

typedef float  f32x4  __attribute__((ext_vector_type(4)));
typedef __bf16 bf16x8 __attribute__((ext_vector_type(8)));

__device__ __forceinline__ uint16_t f2bf(float f) {
  uint32_t u = __float_as_uint(f);
  u += 0x7fffu + ((u >> 16) & 1u);
  return (uint16_t)(u >> 16);
}

// global -> LDS direct copy, 16B per lane. LDS dest = wave-uniform base + lane*16.
__device__ __forceinline__ void gll16(const void* g, void* l) {
  const __attribute__((address_space(1))) uint32_t* ga =
      (const __attribute__((address_space(1))) uint32_t*)(uintptr_t)g;
  __attribute__((address_space(3))) uint32_t* la =
      (__attribute__((address_space(3))) uint32_t*)(uint32_t)(uintptr_t)l;
  __builtin_amdgcn_global_load_lds(ga, la, 16, 0, 0);
}

// ---------- prep: fmap [b][c][h][w] f32 -> Xp [b][q][c] bf16 (padded, zeroed border) ----------
__global__ void k_pad_transpose(const float* __restrict__ fmap, uint16_t* __restrict__ Xp) {
  __shared__ float t[32][33];
  const int b = blockIdx.z;
  const int c0 = blockIdx.y * 32;
  const int p0 = blockIdx.x * 32;
  const int tx = threadIdx.x, ty = threadIdx.y;
  const float* src = fmap + ((size_t)b * CIN + c0) * HW + p0;
#pragma unroll
  for (int i = 0; i < 4; ++i) {
    int cc = ty + i * 8;
    t[cc][tx] = (p0 + tx < HW) ? src[(size_t)cc * HW + tx] : 0.f;
  }
  __syncthreads();
#pragma unroll
  for (int i = 0; i < 4; ++i) {
    int pl = ty + i * 8;
    int p = p0 + pl;
    if (p < HW) {
      int h = p / 37, w = p - h * 37;
      int q = (h + 1) * QW + (w + 1);
      Xp[((size_t)b * QP + q) * CIN + c0 + tx] = f2bf(t[tx][pl]);
    }
  }
}

// ---------- prep: W1 [o][c][3][3] f32 -> Apk [o][r*1024+c] bf16 ----------
__global__ void k_pack_w1(const float* __restrict__ W1, uint16_t* __restrict__ Apk) {
  int idx = blockIdx.x * 256 + threadIdx.x;
  if (idx >= 512 * KTOT) return;
  int o = idx / KTOT, k = idx - o * KTOT;
  int r = k >> 10, c = k & 1023;
  Apk[idx] = f2bf(W1[((size_t)o * CIN + c) * 9 + r]);
}

// ---------- prep: W2 [120][512] f32 -> W2p [128][512] bf16 ----------
__global__ void k_pack_w2(const float* __restrict__ W2, uint16_t* __restrict__ W2p) {
  int idx = blockIdx.x * 256 + threadIdx.x;
  int j = idx >> 9, o = idx & 511;
  W2p[idx] = (j < 120) ? f2bf(W2[j * 512 + o]) : (uint16_t)0;
}

// ---------- conv1: implicit GEMM, forced LDS/MFMA overlap ----------
// Geometry/slots/staging = round 9 (BM192 x BN256 x BK64, 8 waves 2Mx4N,
// A 3x24KB staged t+2, B 2x32KB staged t+1, one barrier + vmcnt(3)/tile).
// Body: all 20 frag ds_reads issue at window top (asm, order bv0,av0,bv1,av1);
// MFMA of PREVIOUS tile's kk1 (frags held in regs across the barrier) runs
// under those reads; counted lgkmcnt(10) gates kk0 MFMA (bv1/av1 stay in
// flight); lgkmcnt(0) completes kk1 frags for the NEXT window. sched_barrier
// after every asm wait (rule: compiler hoists reg-only MFMA past asm waits).
__global__ __launch_bounds__(512, 1) void k_conv1(
    const uint16_t* __restrict__ Xp, const uint16_t* __restrict__ Apk,
    const float* __restrict__ b1, uint16_t* __restrict__ x1) {
  __shared__ __align__(16) uint16_t lds[BBASE + 2 * BSL];   // 139264 B

  const int tid  = threadIdx.x;
  const int wid  = tid >> 6, lane = tid & 63;
  const int lrow = lane & 15, lq = lane >> 4;
  const int wm   = wid >> 2,  wn = wid & 3;           // 2M x 4N

  // grid: 256 blocks = 8 XCDs x 32, mt-major within XCD
  const int bid = blockIdx.x;
  const int g   = (bid & 7) * 32 + (bid >> 3);
  const int mt  = g >> 1, nt = g & 1;
  const int batch = mt >> 3, qb = (mt & 7) * 192;
  const int o0 = nt * 256;
  const uint16_t* Xb = Xp + (size_t)batch * QP * CIN;

  // swizzled fragment column (elements): lds_byte = glob_byte ^ ((row&7)<<4)
  const int xorb    = (lrow & 7) << 4;
  const int col_el0 = ((lq * 16) ^ xorb) >> 1;

  // per-lane frag byte offsets within a slot (kk0); kk1 = ^64 (byte bit 6)
  int a_off[6], b_off[4];
#pragma unroll
  for (int m = 0; m < 6; ++m)
    a_off[m] = ((wm * 96 + m * 16 + lrow) * 64 + col_el0) * 2;
#pragma unroll
  for (int n = 0; n < 4; ++n)
    b_off[n] = ((wn * 64 + n * 16 + lrow) * 64 + col_el0) * 2;

  // staging: srow = tid>>3 (0..63), pre-swizzled source column
  const int scol = ((tid & 7) ^ ((tid >> 3) & 7)) * 8;   // elements
  const int srow = tid >> 3;

  f32x4 acc[6][4] = {};

#define DSREAD(dst, abyte)                                                            \
  asm volatile("ds_read_b128 %0, %1" : "=v"(dst) : "v"(abyte) : "memory")

#define STAGEA(u) do {                                                                \
    if ((u) < NTIL) {                                                                 \
      const int cb_  = (u) / 9;                                                       \
      const int tap_ = (u) - cb_ * 9;                                                 \
      const int off_ = (tap_ / 3) * QW + tap_ % 3;                                    \
      const int c0_  = cb_ << 6;                                                      \
      uint16_t* sl = lds + ((u) % 3) * ASL;                                           \
      _Pragma("unroll")                                                               \
      for (int j = 0; j < 3; ++j)                                                     \
        gll16(Xb + (size_t)(qb + off_ + j * 64 + srow) * CIN + c0_ + scol,            \
              sl + j * 4096 + wid * 512);                                             \
    }                                                                                 \
  } while (0)

#define STAGEB(u) do {                                                                \
    if ((u) < NTIL) {                                                                 \
      const int cb_  = (u) / 9;                                                       \
      const int tap_ = (u) - cb_ * 9;                                                 \
      const int c0_  = cb_ << 6;                                                      \
      uint16_t* sl = lds + BBASE + ((u) & 1) * BSL;                                   \
      _Pragma("unroll")                                                               \
      for (int j = 0; j < 4; ++j)                                                     \
        gll16(Apk + (size_t)(o0 + j * 64 + srow) * KTOT + (tap_ << 10) + c0_ + scol,  \
              sl + j * 4096 + wid * 512);                                             \
    }                                                                                 \
  } while (0)

#define MFMA_SET(AV, BV) do {                                                         \
    __builtin_amdgcn_s_setprio(1);                                                    \
    _Pragma("unroll")                                                                 \
    for (int m = 0; m < 6; ++m)                                                       \
      _Pragma("unroll")                                                               \
      for (int n = 0; n < 4; ++n)                                                     \
        acc[m][n] = __builtin_amdgcn_mfma_f32_16x16x32_bf16(                          \
            AV[m], BV[n], acc[m][n], 0, 0, 0);                                        \
    __builtin_amdgcn_s_setprio(0);                                                    \
  } while (0)

  // WINDOW(T): consume IN (kk1 of T-1), produce OUT (kk1 of T).
#define WINDOW(T, INav, INbv, OUTav, OUTbv, FIRST, LAST) do {                         \
    if (LAST) asm volatile("s_waitcnt vmcnt(0)" ::: "memory");                        \
    else      asm volatile("s_waitcnt vmcnt(3)" ::: "memory");                        \
    asm volatile("s_barrier" ::: "memory");                                           \
    __builtin_amdgcn_sched_barrier(0);                                                \
    const int as_b = ((T) % 3) * 24576;                                               \
    const int bs_b = 73728 + ((T) & 1) * 32768;                                       \
    bf16x8 av0[6], bv0[4];                                                            \
    _Pragma("unroll")                                                                 \
    for (int n = 0; n < 4; ++n) DSREAD(bv0[n], b_off[n] + bs_b);                      \
    _Pragma("unroll")                                                                 \
    for (int m = 0; m < 6; ++m) DSREAD(av0[m], a_off[m] + as_b);                      \
    _Pragma("unroll")                                                                 \
    for (int n = 0; n < 4; ++n) DSREAD(OUTbv[n], (b_off[n] ^ 64) + bs_b);             \
    _Pragma("unroll")                                                                 \
    for (int m = 0; m < 6; ++m) DSREAD(OUTav[m], (a_off[m] ^ 64) + as_b);             \
    STAGEB((T) + 1);                                                                  \
    STAGEA((T) + 2);                                                                  \
    if (!(FIRST)) MFMA_SET(INav, INbv);                                               \
    asm volatile("s_waitcnt lgkmcnt(10)" ::: "memory");                               \
    __builtin_amdgcn_sched_barrier(0);                                                \
    MFMA_SET(av0, bv0);                                                               \
    asm volatile("s_waitcnt lgkmcnt(0)" ::: "memory");                                \
    __builtin_amdgcn_sched_barrier(0);                                                \
  } while (0)

  // prologue: FIFO order B(0), A(0), A(1) -> vmcnt(3) at window 0 drains B(0),A(0)
  STAGEB(0);
  STAGEA(0);
  STAGEA(1);

  bf16x8 avX[6], bvX[4], avY[6], bvY[4];
  WINDOW(0, avY, bvY, avX, bvX, 1, 0);              // produces X (kk1 of tile 0)
  for (int t = 1; t <= NTIL - 3; t += 2) {          // t = 1,3,...,141
    WINDOW(t,     avX, bvX, avY, bvY, 0, 0);
    WINDOW(t + 1, avY, bvY, avX, bvX, 0, 0);
  }
  WINDOW(NTIL - 1, avX, bvX, avY, bvY, 0, 1);       // consumes X, produces Y
  MFMA_SET(avY, bvY);                               // kk1 of last tile

  // epilogue: bias + ReLU6 -> x1 bf16
  const int qr = lq * 4;
#pragma unroll
  for (int n = 0; n < 4; ++n) {
    const int o = o0 + wn * 64 + n * 16 + lrow;
    const float bias = b1[o];
#pragma unroll
    for (int m = 0; m < 6; ++m) {
#pragma unroll
      for (int v = 0; v < 4; ++v) {
        const int q = qb + wm * 96 + m * 16 + qr + v;
        float x = acc[m][n][v] + bias;
        x = fminf(fmaxf(x, 0.f), 6.f);
        x1[((size_t)batch * QT + q) * CMID + o] = f2bf(x);
      }
    }
  }
#undef WINDOW
#undef MFMA_SET
#undef STAGEB
#undef STAGEA
#undef DSREAD
}

// ---------- conv2: out[b][h][w][j] = sum_o x1[q][o] * W2[j][o] + b2[j] ----------
__global__ __launch_bounds__(256, 2) void k_conv2(
    const uint16_t* __restrict__ x1, const uint16_t* __restrict__ W2p,
    const float* __restrict__ b2, float* __restrict__ out) {
  __shared__ __align__(16) uint16_t lA[128 * 64];
  __shared__ __align__(16) uint16_t lB[128 * 64];
  const int tid = threadIdx.x;
  const int wid = tid >> 6, lane = tid & 63;
  const int b = blockIdx.z, q0 = blockIdx.x * 128;
  const uint16_t* Ab = x1 + (size_t)b * QT * CMID;
  const int wm = wid >> 1, wn = wid & 1;
  const int lrow = lane & 15, lk = (lane >> 4) * 8;
  f32x4 acc[4][4] = {};

  for (int kt = 0; kt < 8; ++kt) {
    const int c0 = kt << 6;
#pragma unroll
    for (int i = 0; i < 4; ++i) {
      int wb = i * 256 + wid * 64;
      int chunk = wb + lane;
      int row = chunk >> 3, ch = chunk & 7;
      gll16(Ab + (size_t)(q0 + row) * CMID + c0 + ch * 8, lA + wb * 8);
      gll16(W2p + (size_t)row * CMID + c0 + ch * 8, lB + wb * 8);
    }
    __syncthreads();
#pragma unroll
    for (int kk = 0; kk < 2; ++kk) {
      bf16x8 av[4], bv[4];
#pragma unroll
      for (int mi = 0; mi < 4; ++mi)
        av[mi] = *(const bf16x8*)(lA + (wm * 64 + mi * 16 + lrow) * 64 + kk * 32 + lk);
#pragma unroll
      for (int ni = 0; ni < 4; ++ni)
        bv[ni] = *(const bf16x8*)(lB + (wn * 64 + ni * 16 + lrow) * 64 + kk * 32 + lk);
#pragma unroll
      for (int mi = 0; mi < 4; ++mi)
#pragma unroll
        for (int ni = 0; ni < 4; ++ni)
          acc[mi][ni] = __builtin_amdgcn_mfma_f32_16x16x32_bf16(av[mi], bv[ni], acc[mi][ni], 0, 0, 0);
    }
    __syncthreads();
  }

  const int qr = (lane >> 4) * 4;
#pragma unroll
  for (int ni = 0; ni < 4; ++ni) {
    int j = wn * 64 + ni * 16 + lrow;
    if (j < 120) {
      float bias = b2[j];
#pragma unroll
      for (int mi = 0; mi < 4; ++mi) {
#pragma unroll
        for (int v = 0; v < 4; ++v) {
          int q = q0 + wm * 64 + mi * 16 + qr + v;
          int h = q / QW, w = q - h * QW;
          if (h < 37 && w < 37) {
            out[((size_t)b * HW + h * 37 + w) * 120 + j] = acc[mi][ni][v] + bias;
          }
        }
      }
    }
  }
}

extern "C" void kernel_launch(void* const* d_in, const int* in_sizes, int n_in,
                              void* d_out, int out_size, void* d_ws, size_t ws_size,
                              hipStream_t stream) {
  const float* fmap = (const float*)d_in[0];
  const float* W1   = (const float*)d_in[1];
  const float* b1   = (const float*)d_in[2];
  const float* W2   = (const float*)d_in[3];
  const float* b2   = (const float*)d_in[4];
  float* out = (float*)d_out;

  uint8_t* ws = (uint8_t*)d_ws;
  const size_t XP_BYTES  = (size_t)16 * QP * CIN * 2;   // 52,953,088
  const size_t W1P_BYTES = (size_t)512 * KTOT * 2;      //  9,437,184
  const size_t W2P_BYTES = (size_t)128 * 512 * 2;       //    131,072
  uint16_t* Xp  = (uint16_t*)ws;
  uint16_t* Apk = (uint16_t*)(ws + XP_BYTES);
  uint16_t* W2p = (uint16_t*)(ws + XP_BYTES + W1P_BYTES);
  uint16_t* x1  = (uint16_t*)(ws + XP_BYTES + W1P_BYTES + W2P_BYTES);

  hipMemsetAsync(Xp, 0, XP_BYTES, stream);
  k_pad_transpose<<<dim3(43, 32, 16), dim3(32, 8), 0, stream>>>(fmap, Xp);
  k_pack_w1<<<dim3((512 * KTOT + 255) / 256), dim3(256), 0, stream>>>(W1, Apk);
  k_pack_w2<<<dim3(256), dim3(256), 0, stream>>>(W2, W2p);
  k_conv1<<<dim3(256), dim3(512), 0, stream>>>(Xp, Apk, b1, x1);
  k_conv2<<<dim3(12, 1, 16), dim3(256), 0, stream>>>(x1, W2p, b2, out);
}

// Round 11
// 252.666 us; speedup vs baseline: 1.2564x; 1.2564x over previous
//
#include <hip/hip_runtime.h>
#include <stdint.h>

#define HW   1369      // 37*37 output pixels
#define QW   39        // padded row width
#define QP   1616      // padded plane rows per (b) in Xp
#define QT   1536      // q rows in x1 (per batch)
#define CIN  1024
#define CMID 512
#define KTOT 9216      // 9 * 1024
#define NTIL 144       // K-tiles: 16 cblocks(64) * 9 taps, cblock-major tap-inner
#define ASL  12288     // A slot stride (elements): 192 x 64 (24 KB)
#define BB   24576     // B region base (elements) = 2 * ASL
#define BSL  8192      // B slot stride (elements): 128 x 64 (16 KB)

typedef float  f32x4  __attribute__((ext_vector_type(4)));
typedef __bf16 bf16x8 __attribute__((ext_vector_type(8)));

__device__ __forceinline__ uint16_t f2bf(float f) {
  uint32_t u = __float_as_uint(f);
  u += 0x7fffu + ((u >> 16) & 1u);
  return (uint16_t)(u >> 16);
}

// global -> LDS direct copy, 16B per lane. LDS dest = wave-uniform base + lane*16.
__device__ __forceinline__ void gll16(const void* g, void* l) {
  const __attribute__((address_space(1))) uint32_t* ga =
      (const __attribute__((address_space(1))) uint32_t*)(uintptr_t)g;
  __attribute__((address_space(3))) uint32_t* la =
      (__attribute__((address_space(3))) uint32_t*)(uint32_t)(uintptr_t)l;
  __builtin_amdgcn_global_load_lds(ga, la, 16, 0, 0);
}

// ---------- prep: fmap [b][c][h][w] f32 -> Xp [b][q][c] bf16 (padded, zeroed border) ----------
__global__ void k_pad_transpose(const float* __restrict__ fmap, uint16_t* __restrict__ Xp) {
  __shared__ float t[32][33];
  const int b = blockIdx.z;
  const int c0 = blockIdx.y * 32;
  const int p0 = blockIdx.x * 32;
  const int tx = threadIdx.x, ty = threadIdx.y;
  const float* src = fmap + ((size_t)b * CIN + c0) * HW + p0;
#pragma unroll
  for (int i = 0; i < 4; ++i) {
    int cc = ty + i * 8;
    t[cc][tx] = (p0 + tx < HW) ? src[(size_t)cc * HW + tx] : 0.f;
  }
  __syncthreads();
#pragma unroll
  for (int i = 0; i < 4; ++i) {
    int pl = ty + i * 8;
    int p = p0 + pl;
    if (p < HW) {
      int h = p / 37, w = p - h * 37;
      int q = (h + 1) * QW + (w + 1);
      Xp[((size_t)b * QP + q) * CIN + c0 + tx] = f2bf(t[tx][pl]);
    }
  }
}

// ---------- prep: W1 [o][c][3][3] f32 -> Apk [o][r*1024+c] bf16 ----------
__global__ void k_pack_w1(const float* __restrict__ W1, uint16_t* __restrict__ Apk) {
  int idx = blockIdx.x * 256 + threadIdx.x;
  if (idx >= 512 * KTOT) return;
  int o = idx / KTOT, k = idx - o * KTOT;
  int r = k >> 10, c = k & 1023;
  Apk[idx] = f2bf(W1[((size_t)o * CIN + c) * 9 + r]);
}

// ---------- prep: W2 [120][512] f32 -> W2p [128][512] bf16 ----------
__global__ void k_pack_w2(const float* __restrict__ W2, uint16_t* __restrict__ W2p) {
  int idx = blockIdx.x * 256 + threadIdx.x;
  int j = idx >> 9, o = idx & 511;
  W2p[idx] = (j < 120) ? f2bf(W2[j * 512 + o]) : (uint16_t)0;
}

// ---------- conv1: implicit GEMM, 2 blocks/CU for cross-block pipe overlap ----------
// Block = BM192 x BN128 x BK64, 4 waves (2M x 2N, wave 96x64), LDS 80KB
// (A 2x24KB + B 2x16KB). Grid = 512 = 2 blocks/CU (2x80KB = full 160KB pool).
// Two INDEPENDENT barrier groups per CU: block X's LDS-read stall overlaps
// block Y's MFMA burst (rounds 6-10 showed one barrier group = pipes SUM).
// Stage t+1 into opposite slot -> no mid-tile drain; one vmcnt(0)+barrier/tile;
// plain C++ body (compiler counted-lgkm scheduling, proven best r9 vs r10).
// K-order: t = cblock*9 + tap (tap-inner, A panel L2-hot). T2 XOR swizzle.
__global__ __launch_bounds__(256, 2) void k_conv1(
    const uint16_t* __restrict__ Xp, const uint16_t* __restrict__ Apk,
    const float* __restrict__ b1, uint16_t* __restrict__ x1) {
  __shared__ __align__(16) uint16_t lds[2 * ASL + 2 * BSL];   // 81920 B

  const int tid  = threadIdx.x;
  const int wid  = tid >> 6, lane = tid & 63;
  const int lrow = lane & 15, lq = lane >> 4;
  const int wm   = wid >> 1,  wn = wid & 1;           // 2M x 2N

  // grid: 512 blocks = 8 XCDs x 64, mt-major within XCD (4 nt consecutive)
  const int bid = blockIdx.x;
  const int g   = (bid & 7) * 64 + (bid >> 3);
  const int mt  = g >> 2, nt = g & 3;
  const int batch = mt >> 3, qb = (mt & 7) * 192;
  const int o0 = nt * 128;
  const uint16_t* Xb = Xp + (size_t)batch * QP * CIN;

  // fragment-read swizzled column offsets (elements); lds_byte = glob_byte ^ ((row&7)<<4)
  const int xorb    = (lrow & 7) << 4;
  const int col_el0 = ((lq * 16) ^ xorb) >> 1;   // kk=0
  const int col_el1 = col_el0 ^ 32;              // kk=1 (toggle byte bit 6)

  // staging: 256 threads; srow = tid>>3 (0..31), pre-swizzled source column
  const int scol = ((tid & 7) ^ ((tid >> 3) & 7)) * 8;   // elements
  const int srow = tid >> 3;

  f32x4 acc[6][4] = {};

#define STAGE(u) do {                                                                 \
    if ((u) < NTIL) {                                                                 \
      const int cb_  = (u) / 9;                                                       \
      const int tap_ = (u) - cb_ * 9;                                                 \
      const int off_ = (tap_ / 3) * QW + tap_ % 3;                                    \
      const int c0_  = cb_ << 6;                                                      \
      uint16_t* sa = lds + ((u) & 1) * ASL;                                           \
      uint16_t* sb = lds + BB + ((u) & 1) * BSL;                                      \
      _Pragma("unroll")                                                               \
      for (int j = 0; j < 6; ++j)                                                     \
        gll16(Xb + (size_t)(qb + off_ + j * 32 + srow) * CIN + c0_ + scol,            \
              sa + (j * 256 + wid * 64) * 8);                                         \
      _Pragma("unroll")                                                               \
      for (int j = 0; j < 4; ++j)                                                     \
        gll16(Apk + (size_t)(o0 + j * 32 + srow) * KTOT + (tap_ << 10) + c0_ + scol,  \
              sb + (j * 256 + wid * 64) * 8);                                         \
    }                                                                                 \
  } while (0)

  // prologue: stage tile 0
  STAGE(0);

  for (int t = 0; t < NTIL; ++t) {
    const uint16_t* As = lds + (t & 1) * ASL;
    const uint16_t* Bs = lds + BB + (t & 1) * BSL;
    asm volatile("s_waitcnt vmcnt(0)" ::: "memory");   // stage(t) landed
    asm volatile("s_barrier" ::: "memory");            // all waves see slot t
    __builtin_amdgcn_sched_barrier(0);
    STAGE(t + 1);                                      // opposite slot, no WAR

    bf16x8 av0[6], av1[6], bv0[4], bv1[4];
#pragma unroll
    for (int n = 0; n < 4; ++n) {
      const uint16_t* br = Bs + (wn * 64 + n * 16 + lrow) * 64;
      bv0[n] = *(const bf16x8*)(br + col_el0);
      bv1[n] = *(const bf16x8*)(br + col_el1);
    }
#pragma unroll
    for (int m = 0; m < 6; ++m) {
      const uint16_t* ar = As + (wm * 96 + m * 16 + lrow) * 64;
      av0[m] = *(const bf16x8*)(ar + col_el0);
      av1[m] = *(const bf16x8*)(ar + col_el1);
    }
    __builtin_amdgcn_s_setprio(1);
#pragma unroll
    for (int m = 0; m < 6; ++m)
#pragma unroll
      for (int n = 0; n < 4; ++n)
        acc[m][n] = __builtin_amdgcn_mfma_f32_16x16x32_bf16(av0[m], bv0[n], acc[m][n], 0, 0, 0);
#pragma unroll
    for (int m = 0; m < 6; ++m)
#pragma unroll
      for (int n = 0; n < 4; ++n)
        acc[m][n] = __builtin_amdgcn_mfma_f32_16x16x32_bf16(av1[m], bv1[n], acc[m][n], 0, 0, 0);
    __builtin_amdgcn_s_setprio(0);
  }

  // epilogue: bias + ReLU6 -> x1 bf16
  const int qr = lq * 4;
#pragma unroll
  for (int n = 0; n < 4; ++n) {
    const int o = o0 + wn * 64 + n * 16 + lrow;
    const float bias = b1[o];
#pragma unroll
    for (int m = 0; m < 6; ++m) {
#pragma unroll
      for (int v = 0; v < 4; ++v) {
        const int q = qb + wm * 96 + m * 16 + qr + v;
        float x = acc[m][n][v] + bias;
        x = fminf(fmaxf(x, 0.f), 6.f);
        x1[((size_t)batch * QT + q) * CMID + o] = f2bf(x);
      }
    }
  }
#undef STAGE
}

// ---------- conv2: out[b][h][w][j] = sum_o x1[q][o] * W2[j][o] + b2[j] ----------
__global__ __launch_bounds__(256, 2) void k_conv2(
    const uint16_t* __restrict__ x1, const uint16_t* __restrict__ W2p,
    const float* __restrict__ b2, float* __restrict__ out) {
  __shared__ __align__(16) uint16_t lA[128 * 64];
  __shared__ __align__(16) uint16_t lB[128 * 64];
  const int tid = threadIdx.x;
  const int wid = tid >> 6, lane = tid & 63;
  const int b = blockIdx.z, q0 = blockIdx.x * 128;
  const uint16_t* Ab = x1 + (size_t)b * QT * CMID;
  const int wm = wid >> 1, wn = wid & 1;
  const int lrow = lane & 15, lk = (lane >> 4) * 8;
  f32x4 acc[4][4] = {};

  for (int kt = 0; kt < 8; ++kt) {
    const int c0 = kt << 6;
#pragma unroll
    for (int i = 0; i < 4; ++i) {
      int wb = i * 256 + wid * 64;
      int chunk = wb + lane;
      int row = chunk >> 3, ch = chunk & 7;
      gll16(Ab + (size_t)(q0 + row) * CMID + c0 + ch * 8, lA + wb * 8);
      gll16(W2p + (size_t)row * CMID + c0 + ch * 8, lB + wb * 8);
    }
    __syncthreads();
#pragma unroll
    for (int kk = 0; kk < 2; ++kk) {
      bf16x8 av[4], bv[4];
#pragma unroll
      for (int mi = 0; mi < 4; ++mi)
        av[mi] = *(const bf16x8*)(lA + (wm * 64 + mi * 16 + lrow) * 64 + kk * 32 + lk);
#pragma unroll
      for (int ni = 0; ni < 4; ++ni)
        bv[ni] = *(const bf16x8*)(lB + (wn * 64 + ni * 16 + lrow) * 64 + kk * 32 + lk);
#pragma unroll
      for (int mi = 0; mi < 4; ++mi)
#pragma unroll
        for (int ni = 0; ni < 4; ++ni)
          acc[mi][ni] = __builtin_amdgcn_mfma_f32_16x16x32_bf16(av[mi], bv[ni], acc[mi][ni], 0, 0, 0);
    }
    __syncthreads();
  }

  const int qr = (lane >> 4) * 4;
#pragma unroll
  for (int ni = 0; ni < 4; ++ni) {
    int j = wn * 64 + ni * 16 + lrow;
    if (j < 120) {
      float bias = b2[j];
#pragma unroll
      for (int mi = 0; mi < 4; ++mi) {
#pragma unroll
        for (int v = 0; v < 4; ++v) {
          int q = q0 + wm * 64 + mi * 16 + qr + v;
          int h = q / QW, w = q - h * QW;
          if (h < 37 && w < 37) {
            out[((size_t)b * HW + h * 37 + w) * 120 + j] = acc[mi][ni][v] + bias;
          }
        }
      }
    }
  }
}

extern "C" void kernel_launch(void* const* d_in, const int* in_sizes, int n_in,
                              void* d_out, int out_size, void* d_ws, size_t ws_size,
                              hipStream_t stream) {
  const float* fmap = (const float*)d_in[0];
  const float* W1   = (const float*)d_in[1];
  const float* b1   = (const float*)d_in[2];
  const float* W2   = (const float*)d_in[3];
  const float* b2   = (const float*)d_in[4];
  float* out = (float*)d_out;

  uint8_t* ws = (uint8_t*)d_ws;
  const size_t XP_BYTES  = (size_t)16 * QP * CIN * 2;   // 52,953,088
  const size_t W1P_BYTES = (size_t)512 * KTOT * 2;      //  9,437,184
  const size_t W2P_BYTES = (size_t)128 * 512 * 2;       //    131,072
  uint16_t* Xp  = (uint16_t*)ws;
  uint16_t* Apk = (uint16_t*)(ws + XP_BYTES);
  uint16_t* W2p = (uint16_t*)(ws + XP_BYTES + W1P_BYTES);
  uint16_t* x1  = (uint16_t*)(ws + XP_BYTES + W1P_BYTES + W2P_BYTES);

  hipMemsetAsync(Xp, 0, XP_BYTES, stream);
  k_pad_transpose<<<dim3(43, 32, 16), dim3(32, 8), 0, stream>>>(fmap, Xp);
  k_pack_w1<<<dim3((512 * KTOT + 255) / 256), dim3(256), 0, stream>>>(W1, Apk);
  k_pack_w2<<<dim3(256), dim3(256), 0, stream>>>(W2, W2p);
  k_conv1<<<dim3(512), dim3(256), 0, stream>>>(Xp, Apk, b1, x1);
  k_conv2<<<dim3(12, 1, 16), dim3(256), 0, stream>>>(x1, W2p, b2, out);
}